// Round 7
// baseline (86216.687 us; speedup 1.0000x reference)
//
#include <hip/hip_runtime.h>
#include <hip/hip_cooperative_groups.h>
#include <cmath>

namespace cg = cooperative_groups;

// ---------- high-accuracy double transcendentals ----------
__device__ __forceinline__ double dexp_(double x) {
    x = fmin(fmax(x, -64.0), 64.0);
    double w = x * 1.4426950408889634;     // log2(e)
    double n = rint(w);
    double u = (w - n) * 0.6931471805599453;
    double p = 1.0 + u * (1.0 + u * (0.5 + u * (1.6666666666666666e-01 +
               u * (4.1666666666666664e-02 + u * (8.3333333333333332e-03 +
               u * (1.3888888888888889e-03 + u * (1.9841269841269841e-04 +
               u * (2.4801587301587302e-05 + u * (2.7557319223985893e-06 +
               u * (2.7557319223985888e-07 + u * 2.5052108385441720e-08))))))))));
    return ldexp(p, (int)n);
}
__device__ __forceinline__ double dtanh_(double x) {
    double ax = fabs(x);
    double e = dexp_(2.0 * ax);
    double t = 1.0 - 2.0 / (e + 1.0);
    return copysign(t, x);
}
__device__ __forceinline__ double dsig_(double x) {
    return 1.0 / (1.0 + dexp_(-x));
}

// ============================================================================
// Cooperative fused kernel: 256 blocks x 512 threads (1 block/CU).
// Per-step math bodies are bit-identical to the r4 kernels.
// ============================================================================
__global__ __launch_bounds__(512, 2) void fused_kernel(
    const float* __restrict__ x, const int* __restrict__ y,
    const float* __restrict__ eWih, const float* __restrict__ eWhh,
    const float* __restrict__ ebih, const float* __restrict__ ebhh,
    const float* __restrict__ dWih, const float* __restrict__ dWhh,
    const float* __restrict__ dbih, const float* __restrict__ dbhh,
    const float* __restrict__ W1, const float* __restrict__ W2,
    const float* __restrict__ V,
    float* __restrict__ out, float* __restrict__ wsf)
{
    double* encW1d = (double*)wsf;              // 1310720
    double* bencR  = encW1d + 1310720;          // 1024
    double* bdecR  = bencR + 1024;              // 1024
    float* enc_out = (float*)(bdecR + 1024);    // [512][256][256] (b,s,h)
    float* c_st    = enc_out + 33554432;        // 131072
    float* hzero   = c_st + 131072;             // 131072
    float* hd      = hzero + 131072;            // 2 x 131072
    float* dibuf   = hd + 262144;               // 131072
    float* logp    = dibuf + 131072;            // 131072
    float* WencR   = logp + 131072;             // 257*1024
    float* WdecR   = WencR + 263168;            // 513*1024

    cg::grid_group grid = cg::this_grid();
    const int tid = threadIdx.x;
    const int bid = blockIdx.x;

    __shared__ float Xs[16 * 516];
    __shared__ float s_h[2][256];
    __shared__ double s_V[2][12];
    __shared__ double s_W2h[2][12];
    __shared__ double s_ld[2][256];
    __shared__ float s_e[2][256];
    __shared__ double s_red[2][4];
    __shared__ int s_redi[2][4];
    __shared__ double s_maxd[2], s_Zd[2];
    __shared__ int s_am[2];
    __shared__ double s_lred[8];

    // ================= phase 0: prep (r4 weight layout) + zero =================
    {
        const int n_enc = 257 * 1024;
        const int n_dec = 513 * 1024;
        const int total = n_enc + n_dec + 2048 + 262144;
        for (int idx = bid * 512 + tid; idx < total; idx += 256 * 512) {
            if (idx < n_enc) {
                int k = idx >> 10, c = idx & 1023;
                int j = c >> 2, g = c & 3, r = g * 256 + j;
                WencR[idx] = (k == 0) ? eWih[r] : eWhh[r * 256 + (k - 1)];
            } else if (idx < n_enc + n_dec) {
                int i2 = idx - n_enc;
                int k = i2 >> 10, c = i2 & 1023;
                int j = c >> 2, g = c & 3, r = g * 256 + j;
                WdecR[i2] = (k < 257) ? dWih[r * 257 + k] : dWhh[r * 256 + (k - 257)];
            } else if (idx < n_enc + n_dec + 2048) {
                int c = idx - n_enc - n_dec;
                if (c < 1024) {
                    int r = (c & 3) * 256 + (c >> 2);
                    bencR[c] = (double)ebih[r] + (double)ebhh[r];
                } else {
                    int c2 = c - 1024;
                    int r = (c2 & 3) * 256 + (c2 >> 2);
                    bdecR[c2] = (double)dbih[r] + (double)dbhh[r];
                }
            } else {
                int j = idx - (n_enc + n_dec + 2048);
                if (j < 131072) c_st[j] = 0.0f;
                else hzero[j - 131072] = 0.0f;
            }
        }
    }
    grid.sync();

    // ================= encoder: 256 steps =================
    {
        const int row = tid & 15;
        const int jt  = tid >> 4;                 // 0..31
        const int b0  = (bid & 31) * 16;
        const int jg  = (bid >> 5) * 32 + jt;     // 0..255
        const float* wp = WencR + jg * 4;

        for (int t = 0; t < 256; ++t) {
            const float* h_in = (t == 0) ? hzero : (enc_out + (long)(t - 1) * 256);
            const long hin_str = (t == 0) ? 256 : 65536;
            float* h_out = enc_out + (long)t * 256;

            #pragma unroll
            for (int i = 0; i < 2; ++i) {
                int idx = tid + i * 512;
                int r = idx >> 6;
                int c4 = (idx & 63) * 4;
                float4 v = *(const float4*)&h_in[(long)(b0 + r) * hin_str + c4];
                *(float4*)&Xs[r * 260 + c4] = v;
            }
            if (tid < 16) Xs[tid * 260 + 256] = x[(b0 + tid) * 256 + t];
            __syncthreads();

            double A0 = 0, A1 = 0, A2 = 0, A3 = 0;
            const float* xr = &Xs[row * 260];
            for (int k0 = 0; k0 < 256; k0 += 8) {
                float4 w[8];
                #pragma unroll
                for (int i = 0; i < 8; ++i)
                    w[i] = *(const float4*)&wp[(1 + k0 + i) * 1024];
                float4 xa = *(const float4*)&xr[k0];
                float4 xb = *(const float4*)&xr[k0 + 4];
                float xs[8] = {xa.x, xa.y, xa.z, xa.w, xb.x, xb.y, xb.z, xb.w};
                float p0 = 0.f, p1 = 0.f, p2 = 0.f, p3 = 0.f;
                #pragma unroll
                for (int i = 0; i < 8; ++i) {
                    p0 = fmaf(w[i].x, xs[i], p0);
                    p1 = fmaf(w[i].y, xs[i], p1);
                    p2 = fmaf(w[i].z, xs[i], p2);
                    p3 = fmaf(w[i].w, xs[i], p3);
                }
                A0 += (double)p0; A1 += (double)p1;
                A2 += (double)p2; A3 += (double)p3;
            }
            {   // k = 0 : x_t
                float4 w = *(const float4*)&wp[0];
                float xv = xr[256];
                A0 += (double)(w.x * xv); A1 += (double)(w.y * xv);
                A2 += (double)(w.z * xv); A3 += (double)(w.w * xv);
            }

            double bi = bencR[jg * 4 + 0], bf = bencR[jg * 4 + 1];
            double bg = bencR[jg * 4 + 2], bo = bencR[jg * 4 + 3];
            int b = b0 + row;
            double iv = dsig_(A0 + bi);
            double fv = dsig_(A1 + bf);
            double gv = dtanh_(A2 + bg);
            double ov = dsig_(A3 + bo);
            long ci = (long)b * 256 + jg;
            double c = fv * (double)c_st[ci] + iv * gv;
            c_st[ci] = (float)c;
            h_out[(long)b * 65536 + jg] = (float)(ov * dtanh_(c));

            grid.sync();
        }
    }

    // ================= encW1 (k-ascending fp64, same bits as r4) =================
    {
        int m = bid * 512 + tid;                  // 0..131071
        const float* er = enc_out + (long)m * 256;
        double acc[10] = {0,0,0,0,0,0,0,0,0,0};
        for (int k = 0; k < 256; ++k) {
            double ev = (double)er[k];
            #pragma unroll
            for (int u = 0; u < 10; ++u)
                acc[u] += ev * (double)W1[u * 256 + k];
        }
        #pragma unroll
        for (int u = 0; u < 10; ++u) encW1d[(long)m * 10 + u] = acc[u];
    }
    grid.sync();

    // ================= decoder: 256 x (att ; sync ; dec ; sync) =================
    {
        const int half = tid >> 8;                // 0/1
        const int s    = tid & 255;
        const int hwid = (tid >> 6) & 3;
        const int lane = tid & 63;
        const int ab   = (bid << 1) | half;       // att batch row

        const int drow = tid & 15;
        const int djt  = tid >> 4;                // 0..31
        const int db0  = (bid & 31) * 16;
        const int djg  = (bid >> 5) * 32 + djt;
        const float* dwp = WdecR + djg * 4;

        for (int t = 0; t < 256; ++t) {
            const float* h_in; long hin_str;
            if (t == 0) { h_in = enc_out + 255 * 256; hin_str = 65536; }
            else        { h_in = hd + (t & 1) * 131072; hin_str = 256; }
            float* h_out = hd + ((t + 1) & 1) * 131072;

            // ---------- att: this block handles b = 2*bid, 2*bid+1 ----------
            {
                s_h[half][s] = h_in[(long)ab * hin_str + s];
                if (s < 10) s_V[half][s] = (double)V[s];
                __syncthreads();

                for (int u = hwid; u < 10; u += 4) {
                    double p = 0.0;
                    #pragma unroll
                    for (int i = 0; i < 4; ++i) {
                        int k = lane + i * 64;
                        p += (double)W2[u * 256 + k] * (double)s_h[half][k];
                    }
                    #pragma unroll
                    for (int off = 32; off >= 1; off >>= 1) p += __shfl_down(p, off, 64);
                    if (lane == 0) s_W2h[half][u] = p;
                }
                __syncthreads();

                const double* eW = encW1d + ((long)ab * 256 + s) * 10;
                double l = 0.0;
                #pragma unroll
                for (int u = 0; u < 10; ++u)
                    l += s_V[half][u] * dtanh_(eW[u] + s_W2h[half][u]);
                s_ld[half][s] = l;

                {   // argmax (first-index tie-break)
                    double v = l; int idx = s;
                    #pragma unroll
                    for (int off = 32; off >= 1; off >>= 1) {
                        double v2 = __shfl_down(v, off, 64);
                        int i2 = __shfl_down(idx, off, 64);
                        if (v2 > v || (v2 == v && i2 < idx)) { v = v2; idx = i2; }
                    }
                    if (lane == 0) { s_red[half][hwid] = v; s_redi[half][hwid] = idx; }
                }
                __syncthreads();
                if (s == 0) {
                    double v = s_red[half][0]; int idx = s_redi[half][0];
                    #pragma unroll
                    for (int w = 1; w < 4; ++w) {
                        if (s_red[half][w] > v ||
                            (s_red[half][w] == v && s_redi[half][w] < idx)) {
                            v = s_red[half][w]; idx = s_redi[half][w];
                        }
                    }
                    s_maxd[half] = v; s_am[half] = idx;
                }
                __syncthreads();

                double e = dexp_(l - s_maxd[half]);
                s_e[half][s] = (float)e;
                {
                    double v = e;
                    #pragma unroll
                    for (int off = 32; off >= 1; off >>= 1) v += __shfl_down(v, off, 64);
                    if (lane == 0) s_red[half][hwid] = v;
                }
                __syncthreads();
                if (s == 0) {
                    double Z = s_red[half][0] + s_red[half][1]
                             + s_red[half][2] + s_red[half][3];
                    s_Zd[half] = Z;
                    out[t * 512 + ab] = (float)s_am[half];
                    int yv = y[ab * 256 + t];
                    logp[t * 512 + ab] = (float)(s_ld[half][yv] - s_maxd[half] - log(Z));
                }
                __syncthreads();

                const float rcpZ = (float)(1.0 / s_Zd[half]);
                const float* ep = enc_out + (long)ab * 65536 + s;
                float acc[8] = {0.f,0.f,0.f,0.f,0.f,0.f,0.f,0.f};
                float v[8];
                #pragma unroll
                for (int i = 0; i < 8; ++i) v[i] = ep[i * 256];
                for (int s2 = 0; s2 < 256; s2 += 8) {
                    int sn = (s2 + 8) & 255;
                    float vn[8];
                    #pragma unroll
                    for (int i = 0; i < 8; ++i) vn[i] = ep[(sn + i) * 256];
                    #pragma unroll
                    for (int i = 0; i < 8; ++i)
                        acc[i] = fmaf(s_e[half][s2 + i], v[i], acc[i]);
                    #pragma unroll
                    for (int i = 0; i < 8; ++i) v[i] = vn[i];
                }
                float r01 = acc[0] + acc[1], r23 = acc[2] + acc[3];
                float r45 = acc[4] + acc[5], r67 = acc[6] + acc[7];
                dibuf[ab * 256 + s] = ((r01 + r23) + (r45 + r67)) * rcpZ;
            }
            grid.sync();

            // ---------- dec-lstm (body == r4) ----------
            {
                #pragma unroll
                for (int i = 0; i < 2; ++i) {
                    int idx = tid + i * 512;
                    int r = idx >> 6;
                    int c4 = (idx & 63) * 4;
                    float4 v = *(const float4*)&dibuf[(long)(db0 + r) * 256 + c4];
                    *(float4*)&Xs[r * 516 + c4] = v;
                    float4 u = *(const float4*)&h_in[(long)(db0 + r) * hin_str + c4];
                    *(float4*)&Xs[r * 516 + 260 + c4] = u;
                }
                if (tid < 16) {
                    int b = db0 + tid;
                    float dv = 0.0f;
                    if (t > 0) {
                        int yi = y[b * 256 + (t - 1)];
                        dv = x[b * 256 + yi];
                    }
                    Xs[tid * 516 + 256] = dv;
                }
                __syncthreads();

                double A0 = 0, A1 = 0, A2 = 0, A3 = 0;
                const float* xr = &Xs[drow * 516];

                for (int k0 = 0; k0 < 256; k0 += 8) {
                    float4 w[8];
                    #pragma unroll
                    for (int i = 0; i < 8; ++i)
                        w[i] = *(const float4*)&dwp[(k0 + i) * 1024];
                    float4 xa = *(const float4*)&xr[k0];
                    float4 xb = *(const float4*)&xr[k0 + 4];
                    float xs[8] = {xa.x, xa.y, xa.z, xa.w, xb.x, xb.y, xb.z, xb.w};
                    float p0 = 0.f, p1 = 0.f, p2 = 0.f, p3 = 0.f;
                    #pragma unroll
                    for (int i = 0; i < 8; ++i) {
                        p0 = fmaf(w[i].x, xs[i], p0);
                        p1 = fmaf(w[i].y, xs[i], p1);
                        p2 = fmaf(w[i].z, xs[i], p2);
                        p3 = fmaf(w[i].w, xs[i], p3);
                    }
                    A0 += (double)p0; A1 += (double)p1;
                    A2 += (double)p2; A3 += (double)p3;
                }
                {   // k = 256 : dec_in
                    float4 w = *(const float4*)&dwp[256 * 1024];
                    float xv = xr[256];
                    A0 += (double)(w.x * xv); A1 += (double)(w.y * xv);
                    A2 += (double)(w.z * xv); A3 += (double)(w.w * xv);
                }
                for (int k0 = 0; k0 < 256; k0 += 8) {
                    float4 w[8];
                    #pragma unroll
                    for (int i = 0; i < 8; ++i)
                        w[i] = *(const float4*)&dwp[(257 + k0 + i) * 1024];
                    float4 xa = *(const float4*)&xr[260 + k0];
                    float4 xb = *(const float4*)&xr[260 + k0 + 4];
                    float xs[8] = {xa.x, xa.y, xa.z, xa.w, xb.x, xb.y, xb.z, xb.w};
                    float p0 = 0.f, p1 = 0.f, p2 = 0.f, p3 = 0.f;
                    #pragma unroll
                    for (int i = 0; i < 8; ++i) {
                        p0 = fmaf(w[i].x, xs[i], p0);
                        p1 = fmaf(w[i].y, xs[i], p1);
                        p2 = fmaf(w[i].z, xs[i], p2);
                        p3 = fmaf(w[i].w, xs[i], p3);
                    }
                    A0 += (double)p0; A1 += (double)p1;
                    A2 += (double)p2; A3 += (double)p3;
                }

                double bi = bdecR[djg * 4 + 0], bf = bdecR[djg * 4 + 1];
                double bg = bdecR[djg * 4 + 2], bo = bdecR[djg * 4 + 3];
                int b = db0 + drow;
                double iv = dsig_(A0 + bi);
                double fv = dsig_(A1 + bf);
                double gv = dtanh_(A2 + bg);
                double ov = dsig_(A3 + bo);
                long ci = (long)b * 256 + djg;
                double c = fv * (double)c_st[ci] + iv * gv;
                c_st[ci] = (float)c;
                h_out[ci] = (float)(ov * dtanh_(c));
            }
            grid.sync();
        }
    }

    // ================= loss (block 0) =================
    if (bid == 0) {
        double acc = 0.0;
        for (int i = tid; i < 131072; i += 512) acc += (double)logp[i];
        const int wid = tid >> 6, lane = tid & 63;
        #pragma unroll
        for (int off = 32; off >= 1; off >>= 1) acc += __shfl_down(acc, off, 64);
        if (lane == 0) s_lred[wid] = acc;
        __syncthreads();
        if (tid == 0) {
            double z = 0.0;
            #pragma unroll
            for (int w = 0; w < 8; ++w) z += s_lred[w];
            out[131072] = (float)(-z / (512.0 * 512.0));
        }
    }
}

// ============================================================================
// Fallback path: r4 multi-kernel pipeline (verbatim)
// ============================================================================
__global__ __launch_bounds__(256) void prep_kernel(
    const float* __restrict__ eWih, const float* __restrict__ eWhh,
    const float* __restrict__ ebih, const float* __restrict__ ebhh,
    const float* __restrict__ dWih, const float* __restrict__ dWhh,
    const float* __restrict__ dbih, const float* __restrict__ dbhh,
    float* __restrict__ WencR, double* __restrict__ bencR,
    float* __restrict__ WdecR, double* __restrict__ bdecR)
{
    const int n_enc = 257 * 1024;
    const int n_dec = 513 * 1024;
    const int total = n_enc + n_dec + 2048;
    for (int idx = blockIdx.x * blockDim.x + threadIdx.x; idx < total;
         idx += gridDim.x * blockDim.x) {
        if (idx < n_enc) {
            int k = idx >> 10, c = idx & 1023;
            int j = c >> 2, g = c & 3, r = g * 256 + j;
            WencR[idx] = (k == 0) ? eWih[r] : eWhh[r * 256 + (k - 1)];
        } else if (idx < n_enc + n_dec) {
            int i2 = idx - n_enc;
            int k = i2 >> 10, c = i2 & 1023;
            int j = c >> 2, g = c & 3, r = g * 256 + j;
            WdecR[i2] = (k < 257) ? dWih[r * 257 + k] : dWhh[r * 256 + (k - 257)];
        } else {
            int c = idx - n_enc - n_dec;
            if (c < 1024) {
                int r = (c & 3) * 256 + (c >> 2);
                bencR[c] = (double)ebih[r] + (double)ebhh[r];
            } else {
                int c2 = c - 1024;
                int r = (c2 & 3) * 256 + (c2 >> 2);
                bdecR[c2] = (double)dbih[r] + (double)dbhh[r];
            }
        }
    }
}

__global__ __launch_bounds__(256) void lstm_enc_kernel(
    const float* __restrict__ x, const float* __restrict__ W,
    const double* __restrict__ bR, const float* __restrict__ h_in, long hin_str,
    float* __restrict__ h_out, float* __restrict__ c_st, int t)
{
    __shared__ float Xs[16 * 260];
    const int tid = threadIdx.x;
    const int row = tid & 15;
    const int jt  = tid >> 4;
    const int b0  = (blockIdx.x & 31) * 16;
    const int jg  = (blockIdx.x >> 5) * 16 + jt;

    #pragma unroll
    for (int i = 0; i < 4; ++i) {
        int idx = tid + i * 256;
        int r = idx >> 6;
        int c4 = (idx & 63) * 4;
        float4 v = *(const float4*)&h_in[(long)(b0 + r) * hin_str + c4];
        *(float4*)&Xs[r * 260 + c4] = v;
    }
    if (tid < 16) Xs[tid * 260 + 256] = x[(b0 + tid) * 256 + t];
    __syncthreads();

    const float* wp = W + jg * 4;
    double A0 = 0, A1 = 0, A2 = 0, A3 = 0;
    const float* xr = &Xs[row * 260];
    for (int k0 = 0; k0 < 256; k0 += 8) {
        float4 w[8];
        #pragma unroll
        for (int i = 0; i < 8; ++i)
            w[i] = *(const float4*)&wp[(1 + k0 + i) * 1024];
        float4 xa = *(const float4*)&xr[k0];
        float4 xb = *(const float4*)&xr[k0 + 4];
        float xs[8] = {xa.x, xa.y, xa.z, xa.w, xb.x, xb.y, xb.z, xb.w};
        float p0 = 0.f, p1 = 0.f, p2 = 0.f, p3 = 0.f;
        #pragma unroll
        for (int i = 0; i < 8; ++i) {
            p0 = fmaf(w[i].x, xs[i], p0);
            p1 = fmaf(w[i].y, xs[i], p1);
            p2 = fmaf(w[i].z, xs[i], p2);
            p3 = fmaf(w[i].w, xs[i], p3);
        }
        A0 += (double)p0; A1 += (double)p1;
        A2 += (double)p2; A3 += (double)p3;
    }
    {
        float4 w = *(const float4*)&wp[0];
        float xv = xr[256];
        A0 += (double)(w.x * xv); A1 += (double)(w.y * xv);
        A2 += (double)(w.z * xv); A3 += (double)(w.w * xv);
    }

    double bi = bR[jg * 4 + 0], bf = bR[jg * 4 + 1];
    double bg = bR[jg * 4 + 2], bo = bR[jg * 4 + 3];
    int b = b0 + row;
    double iv = dsig_(A0 + bi);
    double fv = dsig_(A1 + bf);
    double gv = dtanh_(A2 + bg);
    double ov = dsig_(A3 + bo);
    long ci = (long)b * 256 + jg;
    double c = fv * (double)c_st[ci] + iv * gv;
    c_st[ci] = (float)c;
    h_out[(long)b * 65536 + jg] = (float)(ov * dtanh_(c));
}

__global__ __launch_bounds__(256) void encW1_kernel(
    const float* __restrict__ enc_out, const float* __restrict__ W1,
    double* __restrict__ encW1d)
{
    int m = blockIdx.x * 256 + threadIdx.x;
    const float* er = enc_out + (long)m * 256;
    double acc[10] = {0,0,0,0,0,0,0,0,0,0};
    for (int k = 0; k < 256; ++k) {
        double ev = (double)er[k];
        #pragma unroll
        for (int u = 0; u < 10; ++u)
            acc[u] += ev * (double)W1[u * 256 + k];
    }
    #pragma unroll
    for (int u = 0; u < 10; ++u) encW1d[(long)m * 10 + u] = acc[u];
}

__global__ __launch_bounds__(256) void att_kernel(
    const double* __restrict__ encW1d, const float* __restrict__ enc_out,
    const float* __restrict__ W2, const float* __restrict__ V,
    const float* __restrict__ h_in, long hin_str, const int* __restrict__ y,
    float* __restrict__ di, float* __restrict__ logp_buf,
    float* __restrict__ out_pred, int t)
{
    const int b = blockIdx.x;
    const int s = threadIdx.x;
    const int wid = s >> 6, lane = s & 63;

    __shared__ float s_h[256];
    __shared__ double s_V[12];
    __shared__ double s_W2h[12];
    __shared__ double s_ld[256];
    __shared__ float s_e[256];
    __shared__ double s_red[4];
    __shared__ int s_redi[4];
    __shared__ double s_maxd, s_Zd;
    __shared__ int s_am;

    s_h[s] = h_in[(long)b * hin_str + s];
    if (s < 10) s_V[s] = (double)V[s];
    __syncthreads();

    for (int u = wid; u < 10; u += 4) {
        double p = 0.0;
        #pragma unroll
        for (int i = 0; i < 4; ++i) {
            int k = lane + i * 64;
            p += (double)W2[u * 256 + k] * (double)s_h[k];
        }
        #pragma unroll
        for (int off = 32; off >= 1; off >>= 1) p += __shfl_down(p, off, 64);
        if (lane == 0) s_W2h[u] = p;
    }
    __syncthreads();

    const double* eW = encW1d + ((long)b * 256 + s) * 10;
    double l = 0.0;
    #pragma unroll
    for (int u = 0; u < 10; ++u) l += s_V[u] * dtanh_(eW[u] + s_W2h[u]);
    s_ld[s] = l;

    {
        double v = l; int idx = s;
        #pragma unroll
        for (int off = 32; off >= 1; off >>= 1) {
            double v2 = __shfl_down(v, off, 64);
            int i2 = __shfl_down(idx, off, 64);
            if (v2 > v || (v2 == v && i2 < idx)) { v = v2; idx = i2; }
        }
        if (lane == 0) { s_red[wid] = v; s_redi[wid] = idx; }
    }
    __syncthreads();
    if (s == 0) {
        double v = s_red[0]; int idx = s_redi[0];
        #pragma unroll
        for (int w = 1; w < 4; ++w) {
            if (s_red[w] > v || (s_red[w] == v && s_redi[w] < idx)) {
                v = s_red[w]; idx = s_redi[w];
            }
        }
        s_maxd = v; s_am = idx;
    }
    __syncthreads();

    double e = dexp_(l - s_maxd);
    s_e[s] = (float)e;
    {
        double v = e;
        #pragma unroll
        for (int off = 32; off >= 1; off >>= 1) v += __shfl_down(v, off, 64);
        if (lane == 0) s_red[wid] = v;
    }
    __syncthreads();
    if (s == 0) {
        double Z = s_red[0] + s_red[1] + s_red[2] + s_red[3];
        s_Zd = Z;
        out_pred[t * 512 + b] = (float)s_am;
        int yv = y[b * 256 + t];
        logp_buf[t * 512 + b] = (float)(s_ld[yv] - s_maxd - log(Z));
    }
    __syncthreads();

    const float rcpZ = (float)(1.0 / s_Zd);
    const float* ep = enc_out + (long)b * 65536 + s;
    float acc[8] = {0.f,0.f,0.f,0.f,0.f,0.f,0.f,0.f};
    float v[8];
    #pragma unroll
    for (int i = 0; i < 8; ++i) v[i] = ep[i * 256];
    for (int s2 = 0; s2 < 256; s2 += 8) {
        int sn = (s2 + 8) & 255;
        float vn[8];
        #pragma unroll
        for (int i = 0; i < 8; ++i) vn[i] = ep[(sn + i) * 256];
        #pragma unroll
        for (int i = 0; i < 8; ++i) acc[i] = fmaf(s_e[s2 + i], v[i], acc[i]);
        #pragma unroll
        for (int i = 0; i < 8; ++i) v[i] = vn[i];
    }
    float r01 = acc[0] + acc[1], r23 = acc[2] + acc[3];
    float r45 = acc[4] + acc[5], r67 = acc[6] + acc[7];
    di[b * 256 + s] = ((r01 + r23) + (r45 + r67)) * rcpZ;
}

__global__ __launch_bounds__(256) void lstm_dec_kernel(
    const float* __restrict__ x, const int* __restrict__ y,
    const float* __restrict__ W, const double* __restrict__ bR,
    const float* __restrict__ di, const float* __restrict__ h_in, long hin_str,
    float* __restrict__ h_out, float* __restrict__ c_st, int t)
{
    __shared__ float Xs[16 * 516];
    const int tid = threadIdx.x;
    const int row = tid & 15;
    const int jt  = tid >> 4;
    const int b0  = (blockIdx.x & 31) * 16;
    const int jg  = (blockIdx.x >> 5) * 16 + jt;

    #pragma unroll
    for (int i = 0; i < 4; ++i) {
        int idx = tid + i * 256;
        int r = idx >> 6;
        int c4 = (idx & 63) * 4;
        float4 v = *(const float4*)&di[(long)(b0 + r) * 256 + c4];
        *(float4*)&Xs[r * 516 + c4] = v;
        float4 u = *(const float4*)&h_in[(long)(b0 + r) * hin_str + c4];
        *(float4*)&Xs[r * 516 + 260 + c4] = u;
    }
    if (tid < 16) {
        int b = b0 + tid;
        float dv = 0.0f;
        if (t > 0) {
            int yi = y[b * 256 + (t - 1)];
            dv = x[b * 256 + yi];
        }
        Xs[tid * 516 + 256] = dv;
    }
    __syncthreads();

    const float* wp = W + jg * 4;
    double A0 = 0, A1 = 0, A2 = 0, A3 = 0;
    const float* xr = &Xs[row * 516];

    for (int k0 = 0; k0 < 256; k0 += 8) {
        float4 w[8];
        #pragma unroll
        for (int i = 0; i < 8; ++i)
            w[i] = *(const float4*)&wp[(k0 + i) * 1024];
        float4 xa = *(const float4*)&xr[k0];
        float4 xb = *(const float4*)&xr[k0 + 4];
        float xs[8] = {xa.x, xa.y, xa.z, xa.w, xb.x, xb.y, xb.z, xb.w};
        float p0 = 0.f, p1 = 0.f, p2 = 0.f, p3 = 0.f;
        #pragma unroll
        for (int i = 0; i < 8; ++i) {
            p0 = fmaf(w[i].x, xs[i], p0);
            p1 = fmaf(w[i].y, xs[i], p1);
            p2 = fmaf(w[i].z, xs[i], p2);
            p3 = fmaf(w[i].w, xs[i], p3);
        }
        A0 += (double)p0; A1 += (double)p1;
        A2 += (double)p2; A3 += (double)p3;
    }
    {
        float4 w = *(const float4*)&wp[256 * 1024];
        float xv = xr[256];
        A0 += (double)(w.x * xv); A1 += (double)(w.y * xv);
        A2 += (double)(w.z * xv); A3 += (double)(w.w * xv);
    }
    for (int k0 = 0; k0 < 256; k0 += 8) {
        float4 w[8];
        #pragma unroll
        for (int i = 0; i < 8; ++i)
            w[i] = *(const float4*)&wp[(257 + k0 + i) * 1024];
        float4 xa = *(const float4*)&xr[260 + k0];
        float4 xb = *(const float4*)&xr[260 + k0 + 4];
        float xs[8] = {xa.x, xa.y, xa.z, xa.w, xb.x, xb.y, xb.z, xb.w};
        float p0 = 0.f, p1 = 0.f, p2 = 0.f, p3 = 0.f;
        #pragma unroll
        for (int i = 0; i < 8; ++i) {
            p0 = fmaf(w[i].x, xs[i], p0);
            p1 = fmaf(w[i].y, xs[i], p1);
            p2 = fmaf(w[i].z, xs[i], p2);
            p3 = fmaf(w[i].w, xs[i], p3);
        }
        A0 += (double)p0; A1 += (double)p1;
        A2 += (double)p2; A3 += (double)p3;
    }

    double bi = bR[jg * 4 + 0], bf = bR[jg * 4 + 1];
    double bg = bR[jg * 4 + 2], bo = bR[jg * 4 + 3];
    int b = b0 + row;
    double iv = dsig_(A0 + bi);
    double fv = dsig_(A1 + bf);
    double gv = dtanh_(A2 + bg);
    double ov = dsig_(A3 + bo);
    long ci = (long)b * 256 + jg;
    double c = fv * (double)c_st[ci] + iv * gv;
    c_st[ci] = (float)c;
    h_out[ci] = (float)(ov * dtanh_(c));
}

__global__ __launch_bounds__(256) void loss_kernel(
    const float* __restrict__ logp_buf, float* __restrict__ out)
{
    const int tid = threadIdx.x;
    double acc = 0.0;
    for (int i = tid; i < 131072; i += 256) acc += (double)logp_buf[i];
    __shared__ double s_red[4];
    const int wid = tid >> 6, lane = tid & 63;
    #pragma unroll
    for (int off = 32; off >= 1; off >>= 1) acc += __shfl_down(acc, off, 64);
    if (lane == 0) s_red[wid] = acc;
    __syncthreads();
    if (tid == 0) {
        out[131072] = (float)(-(s_red[0] + s_red[1] + s_red[2] + s_red[3])
                              / (512.0 * 512.0));
    }
}

extern "C" void kernel_launch(void* const* d_in, const int* in_sizes, int n_in,
                              void* d_out, int out_size, void* d_ws, size_t ws_size,
                              hipStream_t stream)
{
    const float* x    = (const float*)d_in[0];
    const int*   y    = (const int*)  d_in[1];
    const float* eWih = (const float*)d_in[2];
    const float* eWhh = (const float*)d_in[3];
    const float* ebih = (const float*)d_in[4];
    const float* ebhh = (const float*)d_in[5];
    const float* dWih = (const float*)d_in[6];
    const float* dWhh = (const float*)d_in[7];
    const float* dbih = (const float*)d_in[8];
    const float* dbhh = (const float*)d_in[9];
    const float* W1   = (const float*)d_in[10];
    const float* W2   = (const float*)d_in[11];
    const float* V    = (const float*)d_in[12];
    float* out = (float*)d_out;
    float* wsf = (float*)d_ws;

    double* encW1d = (double*)d_ws;
    double* bencR  = encW1d + 1310720;
    double* bdecR  = bencR + 1024;
    float* enc_out = (float*)(bdecR + 1024);
    float* c_st    = enc_out + 33554432;
    float* hzero   = c_st + 131072;
    float* hd      = hzero + 131072;
    float* dibuf   = hd + 262144;
    float* logp    = dibuf + 131072;
    float* WencR   = logp + 131072;
    float* WdecR   = WencR + 263168;

    void* args[] = {
        (void*)&x, (void*)&y,
        (void*)&eWih, (void*)&eWhh, (void*)&ebih, (void*)&ebhh,
        (void*)&dWih, (void*)&dWhh, (void*)&dbih, (void*)&dbhh,
        (void*)&W1, (void*)&W2, (void*)&V,
        (void*)&out, (void*)&wsf
    };
    hipError_t cerr = hipLaunchCooperativeKernel((void*)fused_kernel,
                                                 dim3(256), dim3(512),
                                                 args, 0, stream);
    if (cerr == hipSuccess) return;

    // -------- fallback: r4 multi-kernel path --------
    hipMemsetAsync(c_st, 0, 131072 * sizeof(float), stream);
    hipMemsetAsync(hzero, 0, 131072 * sizeof(float), stream);

    prep_kernel<<<512, 256, 0, stream>>>(eWih, eWhh, ebih, ebhh,
                                         dWih, dWhh, dbih, dbhh,
                                         WencR, bencR, WdecR, bdecR);

    for (int t = 0; t < 256; ++t) {
        const float* hin; long hstr;
        if (t == 0) { hin = hzero; hstr = 256; }
        else        { hin = enc_out + (long)(t - 1) * 256; hstr = 65536; }
        lstm_enc_kernel<<<512, 256, 0, stream>>>(x, WencR, bencR, hin, hstr,
                                                 enc_out + (long)t * 256, c_st, t);
    }

    encW1_kernel<<<512, 256, 0, stream>>>(enc_out, W1, encW1d);

    for (int t = 0; t < 256; ++t) {
        const float* hin; long hstr;
        if (t == 0) { hin = enc_out + 255 * 256; hstr = 65536; }
        else        { hin = hd + (t & 1) * 131072; hstr = 256; }
        float* hout = hd + ((t + 1) & 1) * 131072;
        att_kernel<<<512, 256, 0, stream>>>(encW1d, enc_out, W2, V, hin, hstr,
                                            y, dibuf, logp, out, t);
        lstm_dec_kernel<<<512, 256, 0, stream>>>(x, y, WdecR, bdecR, dibuf,
                                                 hin, hstr, hout, c_st, t);
    }

    loss_kernel<<<1, 256, 0, stream>>>(logp, out);
}

// Round 8
// 55577.893 us; speedup vs baseline: 1.5513x; 1.5513x over previous
//
#include <hip/hip_runtime.h>
#include <cmath>

// ---------- high-accuracy double transcendentals ----------
__device__ __forceinline__ double dexp_(double x) {
    x = fmin(fmax(x, -64.0), 64.0);
    double w = x * 1.4426950408889634;     // log2(e)
    double n = rint(w);
    double u = (w - n) * 0.6931471805599453;
    double p = 1.0 + u * (1.0 + u * (0.5 + u * (1.6666666666666666e-01 +
               u * (4.1666666666666664e-02 + u * (8.3333333333333332e-03 +
               u * (1.3888888888888889e-03 + u * (1.9841269841269841e-04 +
               u * (2.4801587301587302e-05 + u * (2.7557319223985893e-06 +
               u * (2.7557319223985888e-07 + u * 2.5052108385441720e-08))))))))));
    return ldexp(p, (int)n);
}
__device__ __forceinline__ double dtanh_(double x) {
    double ax = fabs(x);
    double e = dexp_(2.0 * ax);
    double t = 1.0 - 2.0 / (e + 1.0);
    return copysign(t, x);
}
__device__ __forceinline__ double dsig_(double x) {
    return 1.0 / (1.0 + dexp_(-x));
}

// Gate-interleaved transposed weights W[k][j*4+g] (r4 layout), fused biases.
__global__ __launch_bounds__(256) void prep_kernel(
    const float* __restrict__ eWih, const float* __restrict__ eWhh,
    const float* __restrict__ ebih, const float* __restrict__ ebhh,
    const float* __restrict__ dWih, const float* __restrict__ dWhh,
    const float* __restrict__ dbih, const float* __restrict__ dbhh,
    float* __restrict__ WencR, double* __restrict__ bencR,
    float* __restrict__ WdecR, double* __restrict__ bdecR)
{
    const int n_enc = 257 * 1024;
    const int n_dec = 513 * 1024;
    const int total = n_enc + n_dec + 2048;
    for (int idx = blockIdx.x * blockDim.x + threadIdx.x; idx < total;
         idx += gridDim.x * blockDim.x) {
        if (idx < n_enc) {
            int k = idx >> 10, c = idx & 1023;
            int j = c >> 2, g = c & 3, r = g * 256 + j;
            WencR[idx] = (k == 0) ? eWih[r] : eWhh[r * 256 + (k - 1)];
        } else if (idx < n_enc + n_dec) {
            int i2 = idx - n_enc;
            int k = i2 >> 10, c = i2 & 1023;
            int j = c >> 2, g = c & 3, r = g * 256 + j;
            WdecR[i2] = (k < 257) ? dWih[r * 257 + k] : dWhh[r * 256 + (k - 257)];
        } else {
            int c = idx - n_enc - n_dec;
            if (c < 1024) {
                int r = (c & 3) * 256 + (c >> 2);
                bencR[c] = (double)ebih[r] + (double)ebhh[r];
            } else {
                int c2 = c - 1024;
                int r = (c2 & 3) * 256 + (c2 >> 2);
                bdecR[c2] = (double)dbih[r] + (double)dbhh[r];
            }
        }
    }
}

// ============================================================================
// Persistent per-batch kernel: block = 2 batch rows, runs the ENTIRE pipeline
// (256 enc steps, encW1, 256 x att+dec) with only __syncthreads.
// All per-element math bit-identical to r4. No grid-wide sync anywhere.
// ============================================================================
__global__ __launch_bounds__(512) void persist_kernel(
    const float* __restrict__ x, const int* __restrict__ y,
    const float* __restrict__ W1, const float* __restrict__ W2,
    const float* __restrict__ V,
    const float* __restrict__ WencR, const double* __restrict__ bencR,
    const float* __restrict__ WdecR, const double* __restrict__ bdecR,
    float* __restrict__ enc_out, double* __restrict__ encW1d,
    float* __restrict__ logp, float* __restrict__ out)
{
    const int tid = threadIdx.x;
    const int bid = blockIdx.x;
    const int b   = tid >> 8;              // local batch row 0/1
    const int j   = tid & 255;             // gate column / s index
    const int ab  = bid * 2 + b;           // global batch row
    const int hwid = (tid >> 6) & 3;       // wave index within half
    const int lane = tid & 63;

    // Xs[b][0..255]=di, [256]=dec_in, [257]=x_t(enc), [260..515]=h
    __shared__ float Xs[2][516];
    __shared__ double s_V[12];
    __shared__ double s_W2h[2][12];
    __shared__ double s_ld[2][256];
    __shared__ float s_e[2][256];
    __shared__ double s_red[2][4];
    __shared__ int s_redi[2][4];
    __shared__ double s_maxd[2], s_Zd[2];
    __shared__ int s_am[2];

    Xs[b][260 + j] = 0.0f;                 // h0 = 0
    if (tid < 10) s_V[tid] = (double)V[tid];
    float c_reg = 0.0f;                    // c state lives in a register
    __syncthreads();

    // ================= encoder: 256 steps =================
    {
        const float* wp = WencR + j * 4;
        const double bi = bencR[j*4+0], bf = bencR[j*4+1];
        const double bg = bencR[j*4+2], bo = bencR[j*4+3];
        for (int t = 0; t < 256; ++t) {
            if (tid < 2) Xs[tid][257] = x[(bid * 2 + tid) * 256 + t];
            __syncthreads();

            double A0 = 0, A1 = 0, A2 = 0, A3 = 0;
            const float* xr = &Xs[b][260];
            for (int k0 = 0; k0 < 256; k0 += 8) {
                float4 w[8];
                #pragma unroll
                for (int i = 0; i < 8; ++i)
                    w[i] = *(const float4*)&wp[(1 + k0 + i) * 1024];
                float4 xa = *(const float4*)&xr[k0];
                float4 xb = *(const float4*)&xr[k0 + 4];
                float xs[8] = {xa.x, xa.y, xa.z, xa.w, xb.x, xb.y, xb.z, xb.w};
                float p0 = 0.f, p1 = 0.f, p2 = 0.f, p3 = 0.f;
                #pragma unroll
                for (int i = 0; i < 8; ++i) {
                    p0 = fmaf(w[i].x, xs[i], p0);
                    p1 = fmaf(w[i].y, xs[i], p1);
                    p2 = fmaf(w[i].z, xs[i], p2);
                    p3 = fmaf(w[i].w, xs[i], p3);
                }
                A0 += (double)p0; A1 += (double)p1;
                A2 += (double)p2; A3 += (double)p3;
            }
            {   // k = 0 : x_t
                float4 w = *(const float4*)&wp[0];
                float xv = Xs[b][257];
                A0 += (double)(w.x * xv); A1 += (double)(w.y * xv);
                A2 += (double)(w.z * xv); A3 += (double)(w.w * xv);
            }
            double iv = dsig_(A0 + bi);
            double fv = dsig_(A1 + bf);
            double gv = dtanh_(A2 + bg);
            double ov = dsig_(A3 + bo);
            double c = fv * (double)c_reg + iv * gv;
            c_reg = (float)c;
            float hn = (float)(ov * dtanh_(c));
            __syncthreads();
            Xs[b][260 + j] = hn;
            enc_out[(long)ab * 65536 + t * 256 + j] = hn;
        }
    }
    __syncthreads();
    __threadfence_block();

    // ================= encW1 (thread's own rows; k-ascending fp64) =================
    {
        const long m = (long)bid * 512 + tid;      // = ab*256 + j
        const float* er = enc_out + m * 256;
        double acc[10] = {0,0,0,0,0,0,0,0,0,0};
        for (int k = 0; k < 256; ++k) {
            double ev = (double)er[k];
            #pragma unroll
            for (int u = 0; u < 10; ++u)
                acc[u] += ev * (double)W1[u * 256 + k];
        }
        #pragma unroll
        for (int u = 0; u < 10; ++u) encW1d[m * 10 + u] = acc[u];
    }
    __syncthreads();

    // ================= decoder: 256 x (att ; dec) =================
    {
        const float* dwp = WdecR + j * 4;
        const double bi = bdecR[j*4+0], bf = bdecR[j*4+1];
        const double bg = bdecR[j*4+2], bo = bdecR[j*4+3];
        const int s = j;                           // att index alias

        for (int t = 0; t < 256; ++t) {
            __syncthreads();                       // h from prev step visible

            // ---- W2h[u] = dot(W2[u,:], h) ----
            for (int u = hwid; u < 10; u += 4) {
                double p = 0.0;
                #pragma unroll
                for (int i = 0; i < 4; ++i) {
                    int k = lane + i * 64;
                    p += (double)W2[u * 256 + k] * (double)Xs[b][260 + k];
                }
                #pragma unroll
                for (int off = 32; off >= 1; off >>= 1) p += __shfl_down(p, off, 64);
                if (lane == 0) s_W2h[b][u] = p;
            }
            __syncthreads();

            // ---- logits + argmax ----
            const double* eW = encW1d + ((long)ab * 256 + s) * 10;
            double l = 0.0;
            #pragma unroll
            for (int u = 0; u < 10; ++u)
                l += s_V[u] * dtanh_(eW[u] + s_W2h[b][u]);
            s_ld[b][s] = l;
            {
                double v = l; int idx = s;
                #pragma unroll
                for (int off = 32; off >= 1; off >>= 1) {
                    double v2 = __shfl_down(v, off, 64);
                    int i2 = __shfl_down(idx, off, 64);
                    if (v2 > v || (v2 == v && i2 < idx)) { v = v2; idx = i2; }
                }
                if (lane == 0) { s_red[b][hwid] = v; s_redi[b][hwid] = idx; }
            }
            __syncthreads();
            if (s == 0) {
                double v = s_red[b][0]; int idx = s_redi[b][0];
                #pragma unroll
                for (int w = 1; w < 4; ++w) {
                    if (s_red[b][w] > v || (s_red[b][w] == v && s_redi[b][w] < idx)) {
                        v = s_red[b][w]; idx = s_redi[b][w];
                    }
                }
                s_maxd[b] = v; s_am[b] = idx;
            }
            __syncthreads();

            // ---- softmax denom + outputs ----
            double e = dexp_(l - s_maxd[b]);
            s_e[b][s] = (float)e;
            {
                double v = e;
                #pragma unroll
                for (int off = 32; off >= 1; off >>= 1) v += __shfl_down(v, off, 64);
                if (lane == 0) s_red[b][hwid] = v;
            }
            __syncthreads();
            if (s == 0) {
                double Z = s_red[b][0] + s_red[b][1] + s_red[b][2] + s_red[b][3];
                s_Zd[b] = Z;
                out[t * 512 + ab] = (float)s_am[b];
                int yv = y[ab * 256 + t];
                logp[t * 512 + ab] = (float)(s_ld[b][yv] - s_maxd[b] - log(Z));
                // stage dec_in (teacher forcing)
                float dv = 0.0f;
                if (t > 0) {
                    int yi = y[ab * 256 + (t - 1)];
                    dv = x[ab * 256 + yi];
                }
                Xs[b][256] = dv;
            }
            __syncthreads();

            // ---- di[h] = (1/Z) sum_s e[s] * enc_out[b][s][h] (r4 loop) ----
            {
                const float rcpZ = (float)(1.0 / s_Zd[b]);
                const float* ep = enc_out + (long)ab * 65536 + s;
                float acc[8] = {0.f,0.f,0.f,0.f,0.f,0.f,0.f,0.f};
                float v[8];
                #pragma unroll
                for (int i = 0; i < 8; ++i) v[i] = ep[i * 256];
                for (int s2 = 0; s2 < 256; s2 += 8) {
                    int sn = (s2 + 8) & 255;
                    float vn[8];
                    #pragma unroll
                    for (int i = 0; i < 8; ++i) vn[i] = ep[(sn + i) * 256];
                    #pragma unroll
                    for (int i = 0; i < 8; ++i)
                        acc[i] = fmaf(s_e[b][s2 + i], v[i], acc[i]);
                    #pragma unroll
                    for (int i = 0; i < 8; ++i) v[i] = vn[i];
                }
                float r01 = acc[0] + acc[1], r23 = acc[2] + acc[3];
                float r45 = acc[4] + acc[5], r67 = acc[6] + acc[7];
                Xs[b][s] = ((r01 + r23) + (r45 + r67)) * rcpZ;   // di in LDS
            }
            __syncthreads();                       // di + dec_in visible

            // ---- dec LSTM gate dot (r4 regions/order) ----
            double A0 = 0, A1 = 0, A2 = 0, A3 = 0;
            const float* xr = &Xs[b][0];
            for (int k0 = 0; k0 < 256; k0 += 8) {          // region 1: di
                float4 w[8];
                #pragma unroll
                for (int i = 0; i < 8; ++i)
                    w[i] = *(const float4*)&dwp[(k0 + i) * 1024];
                float4 xa = *(const float4*)&xr[k0];
                float4 xb = *(const float4*)&xr[k0 + 4];
                float xs[8] = {xa.x, xa.y, xa.z, xa.w, xb.x, xb.y, xb.z, xb.w};
                float p0 = 0.f, p1 = 0.f, p2 = 0.f, p3 = 0.f;
                #pragma unroll
                for (int i = 0; i < 8; ++i) {
                    p0 = fmaf(w[i].x, xs[i], p0);
                    p1 = fmaf(w[i].y, xs[i], p1);
                    p2 = fmaf(w[i].z, xs[i], p2);
                    p3 = fmaf(w[i].w, xs[i], p3);
                }
                A0 += (double)p0; A1 += (double)p1;
                A2 += (double)p2; A3 += (double)p3;
            }
            {   // k = 256 : dec_in
                float4 w = *(const float4*)&dwp[256 * 1024];
                float xv = xr[256];
                A0 += (double)(w.x * xv); A1 += (double)(w.y * xv);
                A2 += (double)(w.z * xv); A3 += (double)(w.w * xv);
            }
            for (int k0 = 0; k0 < 256; k0 += 8) {          // region 2: h
                float4 w[8];
                #pragma unroll
                for (int i = 0; i < 8; ++i)
                    w[i] = *(const float4*)&dwp[(257 + k0 + i) * 1024];
                float4 xa = *(const float4*)&xr[260 + k0];
                float4 xb = *(const float4*)&xr[260 + k0 + 4];
                float xs[8] = {xa.x, xa.y, xa.z, xa.w, xb.x, xb.y, xb.z, xb.w};
                float p0 = 0.f, p1 = 0.f, p2 = 0.f, p3 = 0.f;
                #pragma unroll
                for (int i = 0; i < 8; ++i) {
                    p0 = fmaf(w[i].x, xs[i], p0);
                    p1 = fmaf(w[i].y, xs[i], p1);
                    p2 = fmaf(w[i].z, xs[i], p2);
                    p3 = fmaf(w[i].w, xs[i], p3);
                }
                A0 += (double)p0; A1 += (double)p1;
                A2 += (double)p2; A3 += (double)p3;
            }

            double iv = dsig_(A0 + bi);
            double fv = dsig_(A1 + bf);
            double gv = dtanh_(A2 + bg);
            double ov = dsig_(A3 + bo);
            double c = fv * (double)c_reg + iv * gv;
            c_reg = (float)c;
            float hn = (float)(ov * dtanh_(c));
            __syncthreads();                       // old h/di reads done
            Xs[b][260 + j] = hn;
        }
    }
}

__global__ __launch_bounds__(256) void loss_kernel(
    const float* __restrict__ logp_buf, float* __restrict__ out)
{
    const int tid = threadIdx.x;
    double acc = 0.0;
    for (int i = tid; i < 131072; i += 256) acc += (double)logp_buf[i];
    __shared__ double s_red[4];
    const int wid = tid >> 6, lane = tid & 63;
    #pragma unroll
    for (int off = 32; off >= 1; off >>= 1) acc += __shfl_down(acc, off, 64);
    if (lane == 0) s_red[wid] = acc;
    __syncthreads();
    if (tid == 0) {
        out[131072] = (float)(-(s_red[0] + s_red[1] + s_red[2] + s_red[3])
                              / (512.0 * 512.0));
    }
}

extern "C" void kernel_launch(void* const* d_in, const int* in_sizes, int n_in,
                              void* d_out, int out_size, void* d_ws, size_t ws_size,
                              hipStream_t stream)
{
    const float* x    = (const float*)d_in[0];
    const int*   y    = (const int*)  d_in[1];
    const float* eWih = (const float*)d_in[2];
    const float* eWhh = (const float*)d_in[3];
    const float* ebih = (const float*)d_in[4];
    const float* ebhh = (const float*)d_in[5];
    const float* dWih = (const float*)d_in[6];
    const float* dWhh = (const float*)d_in[7];
    const float* dbih = (const float*)d_in[8];
    const float* dbhh = (const float*)d_in[9];
    const float* W1   = (const float*)d_in[10];
    const float* W2   = (const float*)d_in[11];
    const float* V    = (const float*)d_in[12];

    double* encW1d = (double*)d_ws;             // 1310720 doubles
    double* bencR  = encW1d + 1310720;          // 1024
    double* bdecR  = bencR + 1024;              // 1024
    float* enc_out = (float*)(bdecR + 1024);    // [512][256][256] (b,s,h)
    float* logp    = enc_out + 33554432;        // 131072
    float* WencR   = logp + 131072;             // 257*1024
    float* WdecR   = WencR + 263168;            // 513*1024

    float* out = (float*)d_out;

    prep_kernel<<<512, 256, 0, stream>>>(eWih, eWhh, ebih, ebhh,
                                         dWih, dWhh, dbih, dbhh,
                                         WencR, bencR, WdecR, bdecR);

    persist_kernel<<<256, 512, 0, stream>>>(x, y, W1, W2, V,
                                            WencR, bencR, WdecR, bdecR,
                                            enc_out, encW1d, logp, out);

    loss_kernel<<<1, 256, 0, stream>>>(logp, out);
}